// Round 8
// baseline (389.982 us; speedup 1.0000x reference)
//
#include <hip/hip_runtime.h>

#define NN 100000
#define NE 1280000
#define K_FEAT 500
#define K_TEXT 384
#define KP 512
#define H 64
#define BM 64
#define BKC 128            // k-span of one staged B chunk (2 K-tiles of 64) -> 16 KB LDS
#define SCAN_BLOCKS 100
#define NODES_PER_SCAN 1000

typedef unsigned short ushort_t;
typedef __attribute__((ext_vector_type(8))) short bf16x8;
typedef __attribute__((ext_vector_type(4))) float f32x4;

template <int V> struct IC { static constexpr int value = V; };

__device__ __forceinline__ ushort_t f2bf(float f) {
    union { float f; unsigned int u; } v; v.f = f;
    unsigned int r = (v.u + 0x7FFFu + ((v.u >> 16) & 1u)) >> 16;  // RNE
    return (ushort_t)r;
}

__device__ __forceinline__ float bf2f(ushort_t u) {
    union { unsigned int i; float f; } v; v.i = ((unsigned int)u) << 16; return v.f;
}

// pack 8 f32 -> 8 bf16 via hardware cvt_pk (RNE)
__device__ __forceinline__ bf16x8 cvt8(float4 a, float4 b) {
    union { bf16x8 v; unsigned int w[4]; } u;
    asm("v_cvt_pk_bf16_f32 %0, %1, %2" : "=v"(u.w[0]) : "v"(a.x), "v"(a.y));
    asm("v_cvt_pk_bf16_f32 %0, %1, %2" : "=v"(u.w[1]) : "v"(a.z), "v"(a.w));
    asm("v_cvt_pk_bf16_f32 %0, %1, %2" : "=v"(u.w[2]) : "v"(b.x), "v"(b.y));
    asm("v_cvt_pk_bf16_f32 %0, %1, %2" : "=v"(u.w[3]) : "v"(b.z), "v"(b.w));
    return u.v;
}

// ---------------- weight fusion (pre-transposed bf16, both padded to [64][512]) ----------------
__global__ void fuse_k(const float* __restrict__ wf, const float* __restrict__ bf,
                       const float* __restrict__ wt, const float* __restrict__ bt,
                       const float* __restrict__ w1,
                       ushort_t* __restrict__ WfxT, ushort_t* __restrict__ WtxT,
                       float* __restrict__ bpre) {
    const int idx = blockIdx.x * 256 + threadIdx.x;
    const int T1 = H * KP;
    const int T2 = 2 * T1;
    if (idx < T1) {
        const int c = idx >> 9, k = idx & 511;
        float s = 0.f;
        if (k < K_FEAT) {
            #pragma unroll 8
            for (int u = 0; u < 64; ++u) s = fmaf(wf[k * 64 + u], w1[u * 64 + c], s);
        }
        WfxT[idx] = f2bf(s);
    } else if (idx < T2) {
        const int r = idx - T1;
        const int c = r >> 9, k = r & 511;
        float s = 0.f;
        if (k < K_TEXT) {
            #pragma unroll 8
            for (int u = 0; u < 64; ++u) s = fmaf(wt[k * 64 + u], w1[(64 + u) * 64 + c], s);
        }
        WtxT[r] = f2bf(s);
    } else if (idx < T2 + H) {
        const int j = idx - T2;
        float s = 0.f;
        for (int u = 0; u < 64; ++u) s = fmaf(bf[u], w1[u * 64 + j], s);
        for (int u = 0; u < 64; ++u) s = fmaf(bt[u], w1[(64 + u) * 64 + j], s);
        bpre[j] = s;
    }
}

// ---------------- degree (edge count per dst) ----------------
__global__ void deg_k(const int* __restrict__ ei, int* __restrict__ deg) {
    const int e = blockIdx.x * 256 + threadIdx.x;
    if (e < NE) atomicAdd(&deg[ei[NE + e]], 1);
}

// ---------------- CSR build ----------------
__global__ __launch_bounds__(256)
void partial_k(const int* __restrict__ deg, int* __restrict__ partial) {
    const int b = blockIdx.x;
    const int base = b * NODES_PER_SCAN;
    const int t = threadIdx.x;
    int s = 0;
    for (int i = t; i < NODES_PER_SCAN; i += 256) s += deg[base + i];
    #pragma unroll
    for (int m = 1; m < 64; m <<= 1) s += __shfl_xor(s, m, 64);
    __shared__ int ws[4];
    if ((t & 63) == 0) ws[t >> 6] = s;
    __syncthreads();
    if (t == 0) partial[b] = ws[0] + ws[1] + ws[2] + ws[3];
}

__global__ void scanp_k(const int* __restrict__ partial, int* __restrict__ psum) {
    __shared__ int buf[SCAN_BLOCKS];
    const int t = threadIdx.x;
    if (t < SCAN_BLOCKS) buf[t] = partial[t];
    __syncthreads();
    if (t == 0) {
        int run = 0;
        for (int i = 0; i < SCAN_BLOCKS; ++i) { int v = buf[i]; buf[i] = run; run += v; }
    }
    __syncthreads();
    if (t < SCAN_BLOCKS) psum[t] = buf[t];
}

// offsets + cursor + dinv (dinv folded in: reads deg anyway)
__global__ __launch_bounds__(256)
void offsets_k(const int* __restrict__ deg, const int* __restrict__ psum,
               int* __restrict__ row_start, int* __restrict__ cursor,
               float* __restrict__ dinv) {
    const int b = blockIdx.x;
    const int base = b * NODES_PER_SCAN;
    const int t = threadIdx.x;
    __shared__ int tsum[256];
    int loc[4];
    int dg[4];
    int s = 0;
    #pragma unroll
    for (int i = 0; i < 4; ++i) {
        loc[i] = s;
        const int n = t * 4 + i;
        dg[i] = (n < NODES_PER_SCAN) ? deg[base + n] : 0;
        s += dg[i];
    }
    tsum[t] = s;
    __syncthreads();
    #pragma unroll
    for (int off = 1; off < 256; off <<= 1) {
        int v = (t >= off) ? tsum[t - off] : 0;
        __syncthreads();
        tsum[t] += v;
        __syncthreads();
    }
    const int texcl = (t == 0) ? 0 : tsum[t - 1];
    const int bp = psum[b];
    #pragma unroll
    for (int i = 0; i < 4; ++i) {
        const int n = t * 4 + i;
        if (n < NODES_PER_SCAN) {
            const int rs = bp + texcl + loc[i];
            row_start[base + n] = rs;
            cursor[base + n] = rs;
            dinv[base + n] = rsqrtf((float)dg[i] + 1.0f);
        }
    }
}

__global__ void sort_k(const int* __restrict__ ei, int* __restrict__ cursor,
                       int* __restrict__ src_sorted) {
    const int e = blockIdx.x * 256 + threadIdx.x;
    if (e < NE) {
        const int s = ei[e];
        const int d = ei[NE + e];
        const int pos = atomicAdd(&cursor[d], 1);
        src_sorted[pos] = s;
    }
}

// ---------------- GEMM1 (MFMA bf16): u1b[N,64] = bf16((x@Wfx + txt@Wtx + bpre) * dinv) ----
// BM=64 -> 1563 blocks; 4 waves x 16 rows. B staged per 16KB chunk (2 K-tiles) into
// XOR-swizzled LDS (both-sides swizzle, 2-way conflicts = free). A read per-lane
// direct to VGPR (coalesced), cvt in-register. 16KB LDS + 64 VGPR -> ~6 blocks/CU
// (grid-limited) ~24 waves/CU for latency hiding.
__global__ __launch_bounds__(256, 8)
void gemm1_mfma(const float* __restrict__ x, const float* __restrict__ txt,
                const ushort_t* __restrict__ WfxT, const ushort_t* __restrict__ WtxT,
                const float* __restrict__ bpre, const float* __restrict__ dinv,
                ushort_t* __restrict__ u1b) {
    __shared__ ushort_t Bs[H * BKC];    // 16 KB, [col][k_local], 256B rows, XOR-swizzled
    char* const ldsb = (char*)Bs;
    const int t = threadIdx.x;
    const int wave = t >> 6, lane = t & 63;
    const int row0 = blockIdx.x * BM;
    const int lr = lane & 15, lq = lane >> 4;

    f32x4 acc[4];
    #pragma unroll
    for (int j = 0; j < 4; ++j) acc[j] = (f32x4){0.f, 0.f, 0.f, 0.f};

    const int rowi = min(row0 + wave * 16 + lr, NN - 1);

    auto phase = [&](const float* __restrict__ A, const ushort_t* __restrict__ WT,
                     auto KD, auto NT_) {
        constexpr int KDIM = decltype(KD)::value;
        constexpr int NTILE = decltype(NT_)::value;            // 64-k tiles
        constexpr int NCHUNK = (NTILE + 1) / 2;
        const float* pa = A + (long)rowi * KDIM;
        for (int chk = 0; chk < NCHUNK; ++chk) {
            __syncthreads();                                   // prev chunk fully consumed
            // ---- stage B chunk: 64 rows x 128 k bf16 = 16 KB (4 x 16B per thread) ----
            #pragma unroll
            for (int i = 0; i < 4; ++i) {
                const int off = (t + i * 256) * 8;             // ushort index in chunk
                const int row = off >> 7;                      // 128 ushorts per row
                bf16x8 v = *(const bf16x8*)(WT + (long)row * KP + chk * BKC + (off & 127));
                *(bf16x8*)(ldsb + ((off * 2) ^ ((row & 7) << 4))) = v;
            }
            __syncthreads();                                   // chunk ready
            const int ntile_c = (chk == NCHUNK - 1) ? (NTILE - 2 * (NCHUNK - 1)) : 2;
            for (int kt = 0; kt < ntile_c; ++kt) {
                #pragma unroll
                for (int ks = 0; ks < 2; ++ks) {
                    const int k = chk * BKC + kt * 64 + ks * 32 + lq * 8;
                    const int k0 = min(k, KDIM - 4);
                    const int k1 = min(k + 4, KDIM - 4);
                    const float4 c0 = *(const float4*)(pa + k0);
                    const float4 c1 = *(const float4*)(pa + k1);
                    const bf16x8 af = cvt8(c0, c1);
                    bf16x8 bfr[4];
                    #pragma unroll
                    for (int cf = 0; cf < 4; ++cf) {
                        const int row = cf * 16 + lr;
                        const int bl = row * 256 + kt * 128 + ks * 64 + lq * 16;
                        bfr[cf] = *(const bf16x8*)(ldsb + (bl ^ ((row & 7) << 4)));
                    }
                    #pragma unroll
                    for (int cf = 0; cf < 4; ++cf)
                        acc[cf] = __builtin_amdgcn_mfma_f32_16x16x32_bf16(
                            af, bfr[cf], acc[cf], 0, 0, 0);
                }
            }
        }
    };

    phase(x, WfxT, IC<K_FEAT>{}, IC<8>{});
    phase(txt, WtxT, IC<K_TEXT>{}, IC<6>{});

    // epilogue: D frag layout col=lane&15, row=(lane>>4)*4+reg; store bf16
    #pragma unroll
    for (int reg = 0; reg < 4; ++reg) {
        const int r = row0 + wave * 16 + lq * 4 + reg;
        if (r < NN) {
            const float di = dinv[r];
            #pragma unroll
            for (int cf = 0; cf < 4; ++cf) {
                const int c = cf * 16 + lr;
                u1b[(long)r * H + c] = f2bf((acc[cf][reg] + bpre[c]) * di);
            }
        }
    }
}

// ---------------- layer1: CSR gather-aggregate (bf16 u1) + relu + 64->7 projection --------
__global__ __launch_bounds__(256)
void layer1_csr_k(const int* __restrict__ row_start, const int* __restrict__ deg,
                  const int* __restrict__ src_sorted, const ushort_t* __restrict__ u1b,
                  const float* __restrict__ dinv, const float* __restrict__ b1,
                  const float* __restrict__ w2, float* __restrict__ u2) {
    const int t = threadIdx.x;
    const int lane = t & 63;
    const int node = blockIdx.x * 4 + (t >> 6);
    if (node >= NN) return;
    const int rs = row_start[node];
    const int dg = deg[node];
    float acc = bf2f(u1b[(long)node * H + lane]);   // self
    for (int j0 = 0; j0 < dg; j0 += 64) {
        const int nj = min(64, dg - j0);
        int sv = 0;
        if (lane < nj) sv = src_sorted[rs + j0 + lane];
        int j = 0;
        for (; j + 4 <= nj; j += 4) {
            const int s0 = __shfl(sv, j, 64);
            const int s1 = __shfl(sv, j + 1, 64);
            const int s2 = __shfl(sv, j + 2, 64);
            const int s3 = __shfl(sv, j + 3, 64);
            const float v0 = bf2f(u1b[(long)s0 * H + lane]);
            const float v1 = bf2f(u1b[(long)s1 * H + lane]);
            const float v2 = bf2f(u1b[(long)s2 * H + lane]);
            const float v3 = bf2f(u1b[(long)s3 * H + lane]);
            acc += v0; acc += v1; acc += v2; acc += v3;
        }
        for (; j < nj; ++j) {
            const int s = __shfl(sv, j, 64);
            acc += bf2f(u1b[(long)s * H + lane]);
        }
    }
    const float di = dinv[node];
    const float h = fmaxf(di * acc + b1[lane], 0.f);
    #pragma unroll
    for (int j = 0; j < 7; ++j) {
        float s = h * w2[lane * 7 + j];
        #pragma unroll
        for (int m = 1; m < 64; m <<= 1) s += __shfl_xor(s, m, 64);
        if (lane == j) u2[node * 8 + j] = di * s;
    }
}

// ---------------- layer2: CSR gather-aggregate + final transform ----------------
__global__ __launch_bounds__(256)
void layer2_csr_k(const int* __restrict__ row_start, const int* __restrict__ deg,
                  const int* __restrict__ src_sorted, const float* __restrict__ u2,
                  const float* __restrict__ dinv, const float* __restrict__ b2,
                  float* __restrict__ out) {
    const int t = threadIdx.x;
    const int c = t & 7;
    const int node = blockIdx.x * 32 + (t >> 3);
    if (node >= NN) return;
    const int rs = row_start[node];
    const int dg = deg[node];
    float acc = (c < 7) ? u2[node * 8 + c] : 0.f;   // self
    int j = 0;
    for (; j + 4 <= dg; j += 4) {
        const int s0 = src_sorted[rs + j];
        const int s1 = src_sorted[rs + j + 1];
        const int s2 = src_sorted[rs + j + 2];
        const int s3 = src_sorted[rs + j + 3];
        if (c < 7) {
            acc += u2[s0 * 8 + c];
            acc += u2[s1 * 8 + c];
            acc += u2[s2 * 8 + c];
            acc += u2[s3 * 8 + c];
        }
    }
    for (; j < dg; ++j) {
        const int s = src_sorted[rs + j];
        if (c < 7) acc += u2[s * 8 + c];
    }
    if (c < 7) out[node * 7 + c] = dinv[node] * acc + b2[c];
}

extern "C" void kernel_launch(void* const* d_in, const int* in_sizes, int n_in,
                              void* d_out, int out_size, void* d_ws, size_t ws_size,
                              hipStream_t stream) {
    const float* x      = (const float*)d_in[0];
    const float* txt    = (const float*)d_in[1];
    const int*   ei     = (const int*)d_in[2];
    const float* w_feat = (const float*)d_in[3];
    const float* b_feat = (const float*)d_in[4];
    const float* w_text = (const float*)d_in[5];
    const float* b_text = (const float*)d_in[6];
    const float* w1     = (const float*)d_in[7];
    const float* b1     = (const float*)d_in[8];
    const float* w2     = (const float*)d_in[9];
    const float* b2     = (const float*)d_in[10];
    float* out = (float*)d_out;

    char* p = (char*)d_ws;
    auto alloc = [&](size_t bytes) {
        char* r = p;
        p += (bytes + 255) & ~(size_t)255;
        return r;
    };
    ushort_t* WfxT = (ushort_t*)alloc((size_t)H * KP * 2);
    ushort_t* WtxT = (ushort_t*)alloc((size_t)H * KP * 2);
    float* bpre = (float*)alloc(H * 4);
    int*   deg  = (int*)alloc((size_t)NN * 4);
    float* dinv = (float*)alloc((size_t)NN * 4);
    int*   row_start = (int*)alloc((size_t)NN * 4);
    int*   cursor    = (int*)alloc((size_t)NN * 4);
    int*   partial   = (int*)alloc((size_t)SCAN_BLOCKS * 4);
    int*   psum      = (int*)alloc((size_t)SCAN_BLOCKS * 4);
    int*   src_sorted = (int*)alloc((size_t)NE * 4);
    ushort_t* u1b = (ushort_t*)alloc((size_t)NN * H * 2);
    float* u2   = (float*)alloc((size_t)NN * 8 * 4);

    hipMemsetAsync(deg, 0, (size_t)NN * 4, stream);

    const int fuse_tot = 2 * H * KP + H;
    fuse_k<<<(fuse_tot + 255) / 256, 256, 0, stream>>>(w_feat, b_feat, w_text, b_text, w1,
                                                       WfxT, WtxT, bpre);
    deg_k<<<(NE + 255) / 256, 256, 0, stream>>>(ei, deg);
    partial_k<<<SCAN_BLOCKS, 256, 0, stream>>>(deg, partial);
    scanp_k<<<1, 128, 0, stream>>>(partial, psum);
    offsets_k<<<SCAN_BLOCKS, 256, 0, stream>>>(deg, psum, row_start, cursor, dinv);
    sort_k<<<(NE + 255) / 256, 256, 0, stream>>>(ei, cursor, src_sorted);
    gemm1_mfma<<<(NN + BM - 1) / BM, 256, 0, stream>>>(x, txt, WfxT, WtxT, bpre, dinv, u1b);
    layer1_csr_k<<<(NN + 3) / 4, 256, 0, stream>>>(row_start, deg, src_sorted, u1b,
                                                   dinv, b1, w2, u2);
    layer2_csr_k<<<(NN + 31) / 32, 256, 0, stream>>>(row_start, deg, src_sorted, u2,
                                                     dinv, b2, out);
}

// Round 9
// 357.253 us; speedup vs baseline: 1.0916x; 1.0916x over previous
//
#include <hip/hip_runtime.h>

#define NN 100000
#define NE 1280000
#define K_FEAT 500
#define K_TEXT 384
#define KP 512
#define H 64
#define BM 64
#define CHUNK 128          // k-floats per staged chunk: A 16KB bf16, B 16KB bf16
#define SCAN_BLOCKS 100
#define NODES_PER_SCAN 1000

typedef unsigned short ushort_t;
typedef __attribute__((ext_vector_type(8))) short bf16x8;
typedef __attribute__((ext_vector_type(4))) float f32x4;

template <int V> struct IC { static constexpr int value = V; };

__device__ __forceinline__ ushort_t f2bf(float f) {
    union { float f; unsigned int u; } v; v.f = f;
    unsigned int r = (v.u + 0x7FFFu + ((v.u >> 16) & 1u)) >> 16;  // RNE
    return (ushort_t)r;
}

__device__ __forceinline__ float bf2f(ushort_t u) {
    union { unsigned int i; float f; } v; v.i = ((unsigned int)u) << 16; return v.f;
}

__device__ __forceinline__ unsigned int cvtpk(float a, float b) {
    unsigned int r;
    asm("v_cvt_pk_bf16_f32 %0, %1, %2" : "=v"(r) : "v"(a), "v"(b));
    return r;
}

// ---------------- weight fusion (pre-transposed bf16, both padded to [64][512]) ----------------
__global__ void fuse_k(const float* __restrict__ wf, const float* __restrict__ bf,
                       const float* __restrict__ wt, const float* __restrict__ bt,
                       const float* __restrict__ w1,
                       ushort_t* __restrict__ WfxT, ushort_t* __restrict__ WtxT,
                       float* __restrict__ bpre) {
    const int idx = blockIdx.x * 256 + threadIdx.x;
    const int T1 = H * KP;
    const int T2 = 2 * T1;
    if (idx < T1) {
        const int c = idx >> 9, k = idx & 511;
        float s = 0.f;
        if (k < K_FEAT) {
            #pragma unroll 8
            for (int u = 0; u < 64; ++u) s = fmaf(wf[k * 64 + u], w1[u * 64 + c], s);
        }
        WfxT[idx] = f2bf(s);
    } else if (idx < T2) {
        const int r = idx - T1;
        const int c = r >> 9, k = r & 511;
        float s = 0.f;
        if (k < K_TEXT) {
            #pragma unroll 8
            for (int u = 0; u < 64; ++u) s = fmaf(wt[k * 64 + u], w1[(64 + u) * 64 + c], s);
        }
        WtxT[r] = f2bf(s);
    } else if (idx < T2 + H) {
        const int j = idx - T2;
        float s = 0.f;
        for (int u = 0; u < 64; ++u) s = fmaf(bf[u], w1[u * 64 + j], s);
        for (int u = 0; u < 64; ++u) s = fmaf(bt[u], w1[(64 + u) * 64 + j], s);
        bpre[j] = s;
    }
}

// ---------------- degree (edge count per dst) ----------------
__global__ void deg_k(const int* __restrict__ ei, int* __restrict__ deg) {
    const int e = blockIdx.x * 256 + threadIdx.x;
    if (e < NE) atomicAdd(&deg[ei[NE + e]], 1);
}

// ---------------- CSR build ----------------
__global__ __launch_bounds__(256)
void partial_k(const int* __restrict__ deg, int* __restrict__ partial) {
    const int b = blockIdx.x;
    const int base = b * NODES_PER_SCAN;
    const int t = threadIdx.x;
    int s = 0;
    for (int i = t; i < NODES_PER_SCAN; i += 256) s += deg[base + i];
    #pragma unroll
    for (int m = 1; m < 64; m <<= 1) s += __shfl_xor(s, m, 64);
    __shared__ int ws[4];
    if ((t & 63) == 0) ws[t >> 6] = s;
    __syncthreads();
    if (t == 0) partial[b] = ws[0] + ws[1] + ws[2] + ws[3];
}

__global__ void scanp_k(const int* __restrict__ partial, int* __restrict__ psum) {
    __shared__ int buf[SCAN_BLOCKS];
    const int t = threadIdx.x;
    if (t < SCAN_BLOCKS) buf[t] = partial[t];
    __syncthreads();
    if (t == 0) {
        int run = 0;
        for (int i = 0; i < SCAN_BLOCKS; ++i) { int v = buf[i]; buf[i] = run; run += v; }
    }
    __syncthreads();
    if (t < SCAN_BLOCKS) psum[t] = buf[t];
}

// offsets + cursor + dinv
__global__ __launch_bounds__(256)
void offsets_k(const int* __restrict__ deg, const int* __restrict__ psum,
               int* __restrict__ row_start, int* __restrict__ cursor,
               float* __restrict__ dinv) {
    const int b = blockIdx.x;
    const int base = b * NODES_PER_SCAN;
    const int t = threadIdx.x;
    __shared__ int tsum[256];
    int loc[4];
    int dg[4];
    int s = 0;
    #pragma unroll
    for (int i = 0; i < 4; ++i) {
        loc[i] = s;
        const int n = t * 4 + i;
        dg[i] = (n < NODES_PER_SCAN) ? deg[base + n] : 0;
        s += dg[i];
    }
    tsum[t] = s;
    __syncthreads();
    #pragma unroll
    for (int off = 1; off < 256; off <<= 1) {
        int v = (t >= off) ? tsum[t - off] : 0;
        __syncthreads();
        tsum[t] += v;
        __syncthreads();
    }
    const int texcl = (t == 0) ? 0 : tsum[t - 1];
    const int bp = psum[b];
    #pragma unroll
    for (int i = 0; i < 4; ++i) {
        const int n = t * 4 + i;
        if (n < NODES_PER_SCAN) {
            const int rs = bp + texcl + loc[i];
            row_start[base + n] = rs;
            cursor[base + n] = rs;
            dinv[base + n] = rsqrtf((float)dg[i] + 1.0f);
        }
    }
}

__global__ void sort_k(const int* __restrict__ ei, int* __restrict__ cursor,
                       int* __restrict__ src_sorted) {
    const int e = blockIdx.x * 256 + threadIdx.x;
    if (e < NE) {
        const int s = ei[e];
        const int d = ei[NE + e];
        const int pos = atomicAdd(&cursor[d], 1);
        src_sorted[pos] = s;
    }
}

// ---------------- GEMM1 (MFMA bf16, DRAM-linear staged A) ----------------
// u1b[N,64] = bf16((x@Wfx + txt@Wtx + bpre) * dinv)
// Per 128-k chunk: A staged 64rows x 128k with 512B-contiguous bursts per row
// (2 rows x 32 lanes x 16B per inst -> DRAM page-friendly), cvt to bf16 in-reg,
// XOR-swizzled LDS (both-sides). B chunk 16KB likewise. Next chunk's global
// loads issued BEFORE compute (latency hides under MFMA). 32KB LDS -> 5 blk/CU.
__global__ __launch_bounds__(256)
void gemm1_mfma(const float* __restrict__ x, const float* __restrict__ txt,
                const ushort_t* __restrict__ WfxT, const ushort_t* __restrict__ WtxT,
                const float* __restrict__ bpre, const float* __restrict__ dinv,
                ushort_t* __restrict__ u1b) {
    __shared__ ushort_t Al[BM * CHUNK];   // 16 KB, [row][k] bf16, 256B rows, XOR-swizzled
    __shared__ ushort_t Bl[H * CHUNK];    // 16 KB, [col][k] bf16, 256B rows, XOR-swizzled
    char* const ldsa = (char*)Al;
    char* const ldsb = (char*)Bl;
    const int t = threadIdx.x;
    const int wave = t >> 6, lane = t & 63;
    const int row0 = blockIdx.x * BM;
    const int lr = lane & 15, lq = lane >> 4;

    // A staging mapping: inst j covers rows j*8 + wave*2 + (lane>>5), 512B/row bursts
    const int s_row = wave * 2 + (lane >> 5);       // 0..7
    const int s_kf = (lane & 31) * 4;               // float offset in chunk

    // B staging mapping (4 insts x 16B, rows of 128 ushorts)
    f32x4 acc[4];
    #pragma unroll
    for (int j = 0; j < 4; ++j) acc[j] = (f32x4){0.f, 0.f, 0.f, 0.f};

    float4 areg[8];
    bf16x8 breg[4];

    auto issueA = [&](const float* __restrict__ A, const int KD, const int k0) {
        #pragma unroll
        for (int j = 0; j < 8; ++j) {
            const int gr = min(row0 + j * 8 + s_row, NN - 1);
            const int kk = min(k0 + s_kf, KD - 4);
            areg[j] = *(const float4*)(A + (long)gr * KD + kk);
        }
    };
    auto issueB = [&](const ushort_t* __restrict__ WT, const int k0) {
        #pragma unroll
        for (int i = 0; i < 4; ++i) {
            const int off = (t + i * 256) * 8;
            const int row = off >> 7;
            breg[i] = *(const bf16x8*)(WT + (long)row * KP + k0 + (off & 127));
        }
    };
    auto writeAB = [&]() {
        #pragma unroll
        for (int j = 0; j < 8; ++j) {
            const int row = j * 8 + s_row;
            const int byteoff = (row * 256 + s_kf * 2) ^ ((row & 7) << 4);
            uint2 w;
            w.x = cvtpk(areg[j].x, areg[j].y);
            w.y = cvtpk(areg[j].z, areg[j].w);
            *(uint2*)(ldsa + byteoff) = w;
        }
        #pragma unroll
        for (int i = 0; i < 4; ++i) {
            const int off = (t + i * 256) * 8;
            const int row = off >> 7;
            *(bf16x8*)(ldsb + ((off * 2) ^ ((row & 7) << 4))) = breg[i];
        }
    };
    auto compute = [&]() {
        #pragma unroll
        for (int kt = 0; kt < 2; ++kt) {
            #pragma unroll
            for (int ks = 0; ks < 2; ++ks) {
                const int kbyte = kt * 128 + ks * 64 + lq * 16;
                const int ra = wave * 16 + lr;
                const bf16x8 af = *(const bf16x8*)(ldsa + ((ra * 256 + kbyte) ^ ((ra & 7) << 4)));
                bf16x8 bfr[4];
                #pragma unroll
                for (int cf = 0; cf < 4; ++cf) {
                    const int col = cf * 16 + lr;
                    bfr[cf] = *(const bf16x8*)(ldsb + ((col * 256 + kbyte) ^ ((col & 7) << 4)));
                }
                #pragma unroll
                for (int cf = 0; cf < 4; ++cf)
                    acc[cf] = __builtin_amdgcn_mfma_f32_16x16x32_bf16(
                        af, bfr[cf], acc[cf], 0, 0, 0);
            }
        }
    };

    auto phase = [&](const float* __restrict__ A, const ushort_t* __restrict__ WT,
                     auto KD_, auto NC_) {
        constexpr int KD = decltype(KD_)::value;
        constexpr int NCHUNK = decltype(NC_)::value;
        issueA(A, KD, 0);
        issueB(WT, 0);
        #pragma unroll
        for (int c = 0; c < NCHUNK; ++c) {
            __syncthreads();                 // prev chunk fully consumed
            writeAB();                       // drains vmcnt for this chunk's loads
            __syncthreads();                 // chunk ready
            if (c + 1 < NCHUNK) {            // issue next chunk's loads early
                issueA(A, KD, (c + 1) * CHUNK);
                issueB(WT, (c + 1) * CHUNK);
            }
            compute();                       // MFMA hides in-flight loads
        }
    };

    phase(x, WfxT, IC<K_FEAT>{}, IC<4>{});
    phase(txt, WtxT, IC<K_TEXT>{}, IC<3>{});

    // epilogue: D frag layout col=lane&15, row=(lane>>4)*4+reg; store bf16
    #pragma unroll
    for (int reg = 0; reg < 4; ++reg) {
        const int r = row0 + wave * 16 + lq * 4 + reg;
        if (r < NN) {
            const float di = dinv[r];
            #pragma unroll
            for (int cf = 0; cf < 4; ++cf) {
                const int c = cf * 16 + lr;
                u1b[(long)r * H + c] = f2bf((acc[cf][reg] + bpre[c]) * di);
            }
        }
    }
}

// ---------------- layer1: CSR gather-aggregate (bf16 u1) + relu + 64->7 projection --------
__global__ __launch_bounds__(256)
void layer1_csr_k(const int* __restrict__ row_start, const int* __restrict__ deg,
                  const int* __restrict__ src_sorted, const ushort_t* __restrict__ u1b,
                  const float* __restrict__ dinv, const float* __restrict__ b1,
                  const float* __restrict__ w2, float* __restrict__ u2) {
    const int t = threadIdx.x;
    const int lane = t & 63;
    const int node = blockIdx.x * 4 + (t >> 6);
    if (node >= NN) return;
    const int rs = row_start[node];
    const int dg = deg[node];
    float acc = bf2f(u1b[(long)node * H + lane]);   // self
    for (int j0 = 0; j0 < dg; j0 += 64) {
        const int nj = min(64, dg - j0);
        int sv = 0;
        if (lane < nj) sv = src_sorted[rs + j0 + lane];
        int j = 0;
        for (; j + 4 <= nj; j += 4) {
            const int s0 = __shfl(sv, j, 64);
            const int s1 = __shfl(sv, j + 1, 64);
            const int s2 = __shfl(sv, j + 2, 64);
            const int s3 = __shfl(sv, j + 3, 64);
            const float v0 = bf2f(u1b[(long)s0 * H + lane]);
            const float v1 = bf2f(u1b[(long)s1 * H + lane]);
            const float v2 = bf2f(u1b[(long)s2 * H + lane]);
            const float v3 = bf2f(u1b[(long)s3 * H + lane]);
            acc += v0; acc += v1; acc += v2; acc += v3;
        }
        for (; j < nj; ++j) {
            const int s = __shfl(sv, j, 64);
            acc += bf2f(u1b[(long)s * H + lane]);
        }
    }
    const float di = dinv[node];
    const float h = fmaxf(di * acc + b1[lane], 0.f);
    #pragma unroll
    for (int j = 0; j < 7; ++j) {
        float s = h * w2[lane * 7 + j];
        #pragma unroll
        for (int m = 1; m < 64; m <<= 1) s += __shfl_xor(s, m, 64);
        if (lane == j) u2[node * 8 + j] = di * s;
    }
}

// ---------------- layer2: CSR gather-aggregate + final transform ----------------
__global__ __launch_bounds__(256)
void layer2_csr_k(const int* __restrict__ row_start, const int* __restrict__ deg,
                  const int* __restrict__ src_sorted, const float* __restrict__ u2,
                  const float* __restrict__ dinv, const float* __restrict__ b2,
                  float* __restrict__ out) {
    const int t = threadIdx.x;
    const int c = t & 7;
    const int node = blockIdx.x * 32 + (t >> 3);
    if (node >= NN) return;
    const int rs = row_start[node];
    const int dg = deg[node];
    float acc = (c < 7) ? u2[node * 8 + c] : 0.f;   // self
    int j = 0;
    for (; j + 4 <= dg; j += 4) {
        const int s0 = src_sorted[rs + j];
        const int s1 = src_sorted[rs + j + 1];
        const int s2 = src_sorted[rs + j + 2];
        const int s3 = src_sorted[rs + j + 3];
        if (c < 7) {
            acc += u2[s0 * 8 + c];
            acc += u2[s1 * 8 + c];
            acc += u2[s2 * 8 + c];
            acc += u2[s3 * 8 + c];
        }
    }
    for (; j < dg; ++j) {
        const int s = src_sorted[rs + j];
        if (c < 7) acc += u2[s * 8 + c];
    }
    if (c < 7) out[node * 7 + c] = dinv[node] * acc + b2[c];
}

extern "C" void kernel_launch(void* const* d_in, const int* in_sizes, int n_in,
                              void* d_out, int out_size, void* d_ws, size_t ws_size,
                              hipStream_t stream) {
    const float* x      = (const float*)d_in[0];
    const float* txt    = (const float*)d_in[1];
    const int*   ei     = (const int*)d_in[2];
    const float* w_feat = (const float*)d_in[3];
    const float* b_feat = (const float*)d_in[4];
    const float* w_text = (const float*)d_in[5];
    const float* b_text = (const float*)d_in[6];
    const float* w1     = (const float*)d_in[7];
    const float* b1     = (const float*)d_in[8];
    const float* w2     = (const float*)d_in[9];
    const float* b2     = (const float*)d_in[10];
    float* out = (float*)d_out;

    char* p = (char*)d_ws;
    auto alloc = [&](size_t bytes) {
        char* r = p;
        p += (bytes + 255) & ~(size_t)255;
        return r;
    };
    ushort_t* WfxT = (ushort_t*)alloc((size_t)H * KP * 2);
    ushort_t* WtxT = (ushort_t*)alloc((size_t)H * KP * 2);
    float* bpre = (float*)alloc(H * 4);
    int*   deg  = (int*)alloc((size_t)NN * 4);
    float* dinv = (float*)alloc((size_t)NN * 4);
    int*   row_start = (int*)alloc((size_t)NN * 4);
    int*   cursor    = (int*)alloc((size_t)NN * 4);
    int*   partial   = (int*)alloc((size_t)SCAN_BLOCKS * 4);
    int*   psum      = (int*)alloc((size_t)SCAN_BLOCKS * 4);
    int*   src_sorted = (int*)alloc((size_t)NE * 4);
    ushort_t* u1b = (ushort_t*)alloc((size_t)NN * H * 2);
    float* u2   = (float*)alloc((size_t)NN * 8 * 4);

    hipMemsetAsync(deg, 0, (size_t)NN * 4, stream);

    const int fuse_tot = 2 * H * KP + H;
    fuse_k<<<(fuse_tot + 255) / 256, 256, 0, stream>>>(w_feat, b_feat, w_text, b_text, w1,
                                                       WfxT, WtxT, bpre);
    deg_k<<<(NE + 255) / 256, 256, 0, stream>>>(ei, deg);
    partial_k<<<SCAN_BLOCKS, 256, 0, stream>>>(deg, partial);
    scanp_k<<<1, 128, 0, stream>>>(partial, psum);
    offsets_k<<<SCAN_BLOCKS, 256, 0, stream>>>(deg, psum, row_start, cursor, dinv);
    sort_k<<<(NE + 255) / 256, 256, 0, stream>>>(ei, cursor, src_sorted);
    gemm1_mfma<<<(NN + BM - 1) / BM, 256, 0, stream>>>(x, txt, WfxT, WtxT, bpre, dinv, u1b);
    layer1_csr_k<<<(NN + 3) / 4, 256, 0, stream>>>(row_start, deg, src_sorted, u1b,
                                                   dinv, b1, w2, u2);
    layer2_csr_k<<<(NN + 31) / 32, 256, 0, stream>>>(row_start, deg, src_sorted, u2,
                                                     dinv, b2, out);
}

// Round 10
// 331.106 us; speedup vs baseline: 1.1778x; 1.0790x over previous
//
#include <hip/hip_runtime.h>

#define NN 100000
#define NE 1280000
#define K_FEAT 500
#define K_TEXT 384
#define KP 512
#define H 64
#define BM 64
#define SCAN_BLOCKS 100
#define NODES_PER_SCAN 1000

typedef unsigned short ushort_t;
typedef __attribute__((ext_vector_type(8))) short bf16x8;
typedef __attribute__((ext_vector_type(4))) float f32x4;

template <int V> struct IC { static constexpr int value = V; };

__device__ __forceinline__ ushort_t f2bf(float f) {
    union { float f; unsigned int u; } v; v.f = f;
    unsigned int r = (v.u + 0x7FFFu + ((v.u >> 16) & 1u)) >> 16;  // RNE
    return (ushort_t)r;
}

__device__ __forceinline__ float bf2f(ushort_t u) {
    union { unsigned int i; float f; } v; v.i = ((unsigned int)u) << 16; return v.f;
}

// pack 8 f32 -> 8 bf16 via hardware cvt_pk (RNE)
__device__ __forceinline__ bf16x8 cvt8(float4 a, float4 b) {
    union { bf16x8 v; unsigned int w[4]; } u;
    asm("v_cvt_pk_bf16_f32 %0, %1, %2" : "=v"(u.w[0]) : "v"(a.x), "v"(a.y));
    asm("v_cvt_pk_bf16_f32 %0, %1, %2" : "=v"(u.w[1]) : "v"(a.z), "v"(a.w));
    asm("v_cvt_pk_bf16_f32 %0, %1, %2" : "=v"(u.w[2]) : "v"(b.x), "v"(b.y));
    asm("v_cvt_pk_bf16_f32 %0, %1, %2" : "=v"(u.w[3]) : "v"(b.z), "v"(b.w));
    return u.v;
}

// ---------------- weight fusion (pre-transposed bf16, both padded to [64][512]) ----------------
__global__ void fuse_k(const float* __restrict__ wf, const float* __restrict__ bf,
                       const float* __restrict__ wt, const float* __restrict__ bt,
                       const float* __restrict__ w1,
                       ushort_t* __restrict__ WfxT, ushort_t* __restrict__ WtxT,
                       float* __restrict__ bpre) {
    const int idx = blockIdx.x * 256 + threadIdx.x;
    const int T1 = H * KP;
    const int T2 = 2 * T1;
    if (idx < T1) {
        const int c = idx >> 9, k = idx & 511;
        float s = 0.f;
        if (k < K_FEAT) {
            #pragma unroll 8
            for (int u = 0; u < 64; ++u) s = fmaf(wf[k * 64 + u], w1[u * 64 + c], s);
        }
        WfxT[idx] = f2bf(s);
    } else if (idx < T2) {
        const int r = idx - T1;
        const int c = r >> 9, k = r & 511;
        float s = 0.f;
        if (k < K_TEXT) {
            #pragma unroll 8
            for (int u = 0; u < 64; ++u) s = fmaf(wt[k * 64 + u], w1[(64 + u) * 64 + c], s);
        }
        WtxT[r] = f2bf(s);
    } else if (idx < T2 + H) {
        const int j = idx - T2;
        float s = 0.f;
        for (int u = 0; u < 64; ++u) s = fmaf(bf[u], w1[u * 64 + j], s);
        for (int u = 0; u < 64; ++u) s = fmaf(bt[u], w1[(64 + u) * 64 + j], s);
        bpre[j] = s;
    }
}

// ---------------- degree (edge count per dst) ----------------
__global__ void deg_k(const int* __restrict__ ei, int* __restrict__ deg) {
    const int e = blockIdx.x * 256 + threadIdx.x;
    if (e < NE) atomicAdd(&deg[ei[NE + e]], 1);
}

// ---------------- CSR build ----------------
__global__ __launch_bounds__(256)
void partial_k(const int* __restrict__ deg, int* __restrict__ partial) {
    const int b = blockIdx.x;
    const int base = b * NODES_PER_SCAN;
    const int t = threadIdx.x;
    int s = 0;
    for (int i = t; i < NODES_PER_SCAN; i += 256) s += deg[base + i];
    #pragma unroll
    for (int m = 1; m < 64; m <<= 1) s += __shfl_xor(s, m, 64);
    __shared__ int ws[4];
    if ((t & 63) == 0) ws[t >> 6] = s;
    __syncthreads();
    if (t == 0) partial[b] = ws[0] + ws[1] + ws[2] + ws[3];
}

__global__ void scanp_k(const int* __restrict__ partial, int* __restrict__ psum) {
    __shared__ int buf[SCAN_BLOCKS];
    const int t = threadIdx.x;
    if (t < SCAN_BLOCKS) buf[t] = partial[t];
    __syncthreads();
    if (t == 0) {
        int run = 0;
        for (int i = 0; i < SCAN_BLOCKS; ++i) { int v = buf[i]; buf[i] = run; run += v; }
    }
    __syncthreads();
    if (t < SCAN_BLOCKS) psum[t] = buf[t];
}

// offsets + cursor + dinv
__global__ __launch_bounds__(256)
void offsets_k(const int* __restrict__ deg, const int* __restrict__ psum,
               int* __restrict__ row_start, int* __restrict__ cursor,
               float* __restrict__ dinv) {
    const int b = blockIdx.x;
    const int base = b * NODES_PER_SCAN;
    const int t = threadIdx.x;
    __shared__ int tsum[256];
    int loc[4];
    int dg[4];
    int s = 0;
    #pragma unroll
    for (int i = 0; i < 4; ++i) {
        loc[i] = s;
        const int n = t * 4 + i;
        dg[i] = (n < NODES_PER_SCAN) ? deg[base + n] : 0;
        s += dg[i];
    }
    tsum[t] = s;
    __syncthreads();
    #pragma unroll
    for (int off = 1; off < 256; off <<= 1) {
        int v = (t >= off) ? tsum[t - off] : 0;
        __syncthreads();
        tsum[t] += v;
        __syncthreads();
    }
    const int texcl = (t == 0) ? 0 : tsum[t - 1];
    const int bp = psum[b];
    #pragma unroll
    for (int i = 0; i < 4; ++i) {
        const int n = t * 4 + i;
        if (n < NODES_PER_SCAN) {
            const int rs = bp + texcl + loc[i];
            row_start[base + n] = rs;
            cursor[base + n] = rs;
            dinv[base + n] = rsqrtf((float)dg[i] + 1.0f);
        }
    }
}

__global__ void sort_k(const int* __restrict__ ei, int* __restrict__ cursor,
                       int* __restrict__ src_sorted) {
    const int e = blockIdx.x * 256 + threadIdx.x;
    if (e < NE) {
        const int s = ei[e];
        const int d = ei[NE + e];
        const int pos = atomicAdd(&cursor[d], 1);
        src_sorted[pos] = s;
    }
}

// ---------------- GEMM1 (MFMA bf16, full global_load_lds DMA, m97 structure) ----------------
// u1b[N,64] = bf16((x@Wfx + txt@Wtx + bpre) * dinv)
// Per 64-k chunk: A 64x64 f32 (16KB) + B 64x64 bf16 (8KB) both DMA'd via
// global_load_lds (in-flight bytes live in the DMA queue, immune to compiler
// load-sinking). 24KB LDS -> 6 blocks/CU: the barrier vmcnt-drain of one block
// hides under 5 other blocks' compute (m114/m97 mechanism). Both tiles use
// pre-swizzled SOURCE + XOR read (rule #21). Nothing is loaded at use.
__global__ __launch_bounds__(256)
void gemm1_mfma(const float* __restrict__ x, const float* __restrict__ txt,
                const ushort_t* __restrict__ WfxT, const ushort_t* __restrict__ WtxT,
                const float* __restrict__ bpre, const float* __restrict__ dinv,
                ushort_t* __restrict__ u1b) {
    __shared__ float As[BM * 64];       // 16 KB [row][k] f32, 256B rows, XOR-swizzled
    __shared__ ushort_t Bs[H * 64];     // 8 KB  [col][k] bf16, 128B rows, XOR-swizzled
    char* const ldsa = (char*)As;
    char* const ldsb = (char*)Bs;
    const int t = threadIdx.x;
    const int wave = t >> 6, lane = t & 63;
    const int row0 = blockIdx.x * BM;
    const int lr = lane & 15, lq = lane >> 4;

    f32x4 acc[4];
    #pragma unroll
    for (int j = 0; j < 4; ++j) acc[j] = (f32x4){0.f, 0.f, 0.f, 0.f};

    auto stageA = [&](const float* __restrict__ A, const int KD, const int k0) {
        #pragma unroll
        for (int p = 0; p < 4; ++p) {
            const int P = p * 4096 + t * 16;               // physical LDS byte
            const int row = P >> 8;                        // 256B per row
            const int kk = ((P & 255) ^ ((row & 7) << 4)) >> 2;  // logical float in row
            const int gk = min(k0 + kk, KD - 4);           // tail clamp (B pad is 0)
            const int gr = min(row0 + row, NN - 1);
            __builtin_amdgcn_global_load_lds(
                (const __attribute__((address_space(1))) void*)(A + (long)gr * KD + gk),
                (__attribute__((address_space(3))) void*)(ldsa + P), 16, 0, 0);
        }
    };
    auto stageB = [&](const ushort_t* __restrict__ WT, const int k0) {
        #pragma unroll
        for (int p = 0; p < 2; ++p) {
            const int P = p * 4096 + t * 16;
            const int row = P >> 7;                        // 128B per row
            const int kkb = (P & 127) ^ ((row & 7) << 4);  // logical byte in row
            __builtin_amdgcn_global_load_lds(
                (const __attribute__((address_space(1))) void*)(WT + (long)row * KP + k0 + (kkb >> 1)),
                (__attribute__((address_space(3))) void*)(ldsb + P), 16, 0, 0);
        }
    };
    auto compute = [&]() {
        #pragma unroll
        for (int ks = 0; ks < 2; ++ks) {
            const int ra = wave * 16 + lr;
            const int ka = ks * 128 + lq * 32;
            const int xa = (ra & 7) << 4;
            const float4 c0 = *(const float4*)(ldsa + ra * 256 + (ka ^ xa));
            const float4 c1 = *(const float4*)(ldsa + ra * 256 + ((ka + 16) ^ xa));
            const bf16x8 af = cvt8(c0, c1);
            bf16x8 bfr[4];
            #pragma unroll
            for (int cf = 0; cf < 4; ++cf) {
                const int col = cf * 16 + lr;
                const int kb = ks * 64 + lq * 16;
                bfr[cf] = *(const bf16x8*)(ldsb + col * 128 + (kb ^ ((col & 7) << 4)));
            }
            #pragma unroll
            for (int cf = 0; cf < 4; ++cf)
                acc[cf] = __builtin_amdgcn_mfma_f32_16x16x32_bf16(
                    af, bfr[cf], acc[cf], 0, 0, 0);
        }
    };

    auto phase = [&](const float* __restrict__ A, const ushort_t* __restrict__ WT,
                     auto KD_, auto NT_) {
        constexpr int KD = decltype(KD_)::value;
        constexpr int NT = decltype(NT_)::value;
        stageA(A, KD, 0);
        stageB(WT, 0);
        for (int kt = 0; kt < NT; ++kt) {
            __syncthreads();                 // DMA(kt) drained, all waves aligned
            compute();
            __syncthreads();                 // all waves done reading chunk kt
            if (kt + 1 < NT) {
                stageA(A, KD, (kt + 1) * 64);
                stageB(WT, (kt + 1) * 64);
            }
        }
    };

    phase(x, WfxT, IC<K_FEAT>{}, IC<8>{});
    phase(txt, WtxT, IC<K_TEXT>{}, IC<6>{});

    // epilogue: D frag layout col=lane&15, row=(lane>>4)*4+reg; store bf16
    #pragma unroll
    for (int reg = 0; reg < 4; ++reg) {
        const int r = row0 + wave * 16 + lq * 4 + reg;
        if (r < NN) {
            const float di = dinv[r];
            #pragma unroll
            for (int cf = 0; cf < 4; ++cf) {
                const int c = cf * 16 + lr;
                u1b[(long)r * H + c] = f2bf((acc[cf][reg] + bpre[c]) * di);
            }
        }
    }
}

// ---------------- layer1: CSR gather (8 lanes/node, bf16x8 vectorized) + relu + 64->7 ------
// 8 nodes per wave; lane = (group g = lane>>3, channel octet c8 = lane&7).
// Each gather = 16B/lane, 8 lanes cover the 128B u1b row; 8 independent gather
// chains per wave (8x MLP vs 1-node-per-wave). Projection: per-lane 8-ch FMA
// then 3-step 8-lane shuffle reduce (vs 42 full-wave shuffles).
__global__ __launch_bounds__(256)
void layer1_csr_k(const int* __restrict__ row_start, const int* __restrict__ deg,
                  const int* __restrict__ src_sorted, const ushort_t* __restrict__ u1b,
                  const float* __restrict__ dinv, const float* __restrict__ b1,
                  const float* __restrict__ w2, float* __restrict__ u2) {
    const int t = threadIdx.x;
    const int lane = t & 63;
    const int g = lane >> 3;
    const int c8 = lane & 7;
    const int node = blockIdx.x * 32 + (t >> 6) * 8 + g;
    if (node >= NN) return;
    const int rs = row_start[node];
    const int dg = deg[node];

    float acc8[8];
    {
        const bf16x8 v = *(const bf16x8*)(u1b + (long)node * H + c8 * 8);
        #pragma unroll
        for (int c = 0; c < 8; ++c) acc8[c] = bf2f((ushort_t)v[c]);
    }
    int j = 0;
    for (; j + 2 <= dg; j += 2) {
        const int s0 = src_sorted[rs + j];
        const int s1 = src_sorted[rs + j + 1];
        const bf16x8 v0 = *(const bf16x8*)(u1b + (long)s0 * H + c8 * 8);
        const bf16x8 v1 = *(const bf16x8*)(u1b + (long)s1 * H + c8 * 8);
        #pragma unroll
        for (int c = 0; c < 8; ++c)
            acc8[c] += bf2f((ushort_t)v0[c]) + bf2f((ushort_t)v1[c]);
    }
    if (j < dg) {
        const int s0 = src_sorted[rs + j];
        const bf16x8 v0 = *(const bf16x8*)(u1b + (long)s0 * H + c8 * 8);
        #pragma unroll
        for (int c = 0; c < 8; ++c) acc8[c] += bf2f((ushort_t)v0[c]);
    }
    const float di = dinv[node];
    float h[8];
    #pragma unroll
    for (int c = 0; c < 8; ++c)
        h[c] = fmaxf(fmaf(di, acc8[c], b1[c8 * 8 + c]), 0.f);
    #pragma unroll
    for (int jj = 0; jj < 7; ++jj) {
        float s = 0.f;
        #pragma unroll
        for (int c = 0; c < 8; ++c)
            s = fmaf(h[c], w2[(c8 * 8 + c) * 7 + jj], s);
        s += __shfl_xor(s, 1, 64);
        s += __shfl_xor(s, 2, 64);
        s += __shfl_xor(s, 4, 64);
        if (c8 == jj) u2[node * 8 + jj] = di * s;
    }
}

// ---------------- layer2: CSR gather-aggregate + final transform ----------------
__global__ __launch_bounds__(256)
void layer2_csr_k(const int* __restrict__ row_start, const int* __restrict__ deg,
                  const int* __restrict__ src_sorted, const float* __restrict__ u2,
                  const float* __restrict__ dinv, const float* __restrict__ b2,
                  float* __restrict__ out) {
    const int t = threadIdx.x;
    const int c = t & 7;
    const int node = blockIdx.x * 32 + (t >> 3);
    if (node >= NN) return;
    const int rs = row_start[node];
    const int dg = deg[node];
    float acc = (c < 7) ? u2[node * 8 + c] : 0.f;   // self
    int j = 0;
    for (; j + 4 <= dg; j += 4) {
        const int s0 = src_sorted[rs + j];
        const int s1 = src_sorted[rs + j + 1];
        const int s2 = src_sorted[rs + j + 2];
        const int s3 = src_sorted[rs + j + 3];
        if (c < 7) {
            acc += u2[s0 * 8 + c];
            acc += u2[s1 * 8 + c];
            acc += u2[s2 * 8 + c];
            acc += u2[s3 * 8 + c];
        }
    }
    for (; j < dg; ++j) {
        const int s = src_sorted[rs + j];
        if (c < 7) acc += u2[s * 8 + c];
    }
    if (c < 7) out[node * 7 + c] = dinv[node] * acc + b2[c];
}

extern "C" void kernel_launch(void* const* d_in, const int* in_sizes, int n_in,
                              void* d_out, int out_size, void* d_ws, size_t ws_size,
                              hipStream_t stream) {
    const float* x      = (const float*)d_in[0];
    const float* txt    = (const float*)d_in[1];
    const int*   ei     = (const int*)d_in[2];
    const float* w_feat = (const float*)d_in[3];
    const float* b_feat = (const float*)d_in[4];
    const float* w_text = (const float*)d_in[5];
    const float* b_text = (const float*)d_in[6];
    const float* w1     = (const float*)d_in[7];
    const float* b1     = (const float*)d_in[8];
    const float* w2     = (const float*)d_in[9];
    const float* b2     = (const float*)d_in[10];
    float* out = (float*)d_out;

    char* p = (char*)d_ws;
    auto alloc = [&](size_t bytes) {
        char* r = p;
        p += (bytes + 255) & ~(size_t)255;
        return r;
    };
    ushort_t* WfxT = (ushort_t*)alloc((size_t)H * KP * 2);
    ushort_t* WtxT = (ushort_t*)alloc((size_t)H * KP * 2);
    float* bpre = (float*)alloc(H * 4);
    int*   deg  = (int*)alloc((size_t)NN * 4);
    float* dinv = (float*)alloc((size_t)NN * 4);
    int*   row_start = (int*)alloc((size_t)NN * 4);
    int*   cursor    = (int*)alloc((size_t)NN * 4);
    int*   partial   = (int*)alloc((size_t)SCAN_BLOCKS * 4);
    int*   psum      = (int*)alloc((size_t)SCAN_BLOCKS * 4);
    int*   src_sorted = (int*)alloc((size_t)NE * 4);
    ushort_t* u1b = (ushort_t*)alloc((size_t)NN * H * 2);
    float* u2   = (float*)alloc((size_t)NN * 8 * 4);

    hipMemsetAsync(deg, 0, (size_t)NN * 4, stream);

    const int fuse_tot = 2 * H * KP + H;
    fuse_k<<<(fuse_tot + 255) / 256, 256, 0, stream>>>(w_feat, b_feat, w_text, b_text, w1,
                                                       WfxT, WtxT, bpre);
    deg_k<<<(NE + 255) / 256, 256, 0, stream>>>(ei, deg);
    partial_k<<<SCAN_BLOCKS, 256, 0, stream>>>(deg, partial);
    scanp_k<<<1, 128, 0, stream>>>(partial, psum);
    offsets_k<<<SCAN_BLOCKS, 256, 0, stream>>>(deg, psum, row_start, cursor, dinv);
    sort_k<<<(NE + 255) / 256, 256, 0, stream>>>(ei, cursor, src_sorted);
    gemm1_mfma<<<(NN + BM - 1) / BM, 256, 0, stream>>>(x, txt, WfxT, WtxT, bpre, dinv, u1b);
    layer1_csr_k<<<(NN + 31) / 32, 256, 0, stream>>>(row_start, deg, src_sorted, u1b,
                                                     dinv, b1, w2, u2);
    layer2_csr_k<<<(NN + 31) / 32, 256, 0, stream>>>(row_start, deg, src_sorted, u2,
                                                     dinv, b2, out);
}

// Round 11
// 325.913 us; speedup vs baseline: 1.1966x; 1.0159x over previous
//
#include <hip/hip_runtime.h>

#define NN 100000
#define NE 1280000
#define K_FEAT 500
#define K_TEXT 384
#define KP 512
#define H 64
#define BM 64
#define SCAN_BLOCKS 100
#define NODES_PER_SCAN 1000
#define FUSE_BLOCKS 257

typedef unsigned short ushort_t;
typedef __attribute__((ext_vector_type(8))) short bf16x8;
typedef __attribute__((ext_vector_type(4))) float f32x4;

template <int V> struct IC { static constexpr int value = V; };

__device__ __forceinline__ ushort_t f2bf(float f) {
    union { float f; unsigned int u; } v; v.f = f;
    unsigned int r = (v.u + 0x7FFFu + ((v.u >> 16) & 1u)) >> 16;  // RNE
    return (ushort_t)r;
}

__device__ __forceinline__ float bf2f(ushort_t u) {
    union { unsigned int i; float f; } v; v.i = ((unsigned int)u) << 16; return v.f;
}

// pack 8 f32 -> 8 bf16 via hardware cvt_pk (RNE)
__device__ __forceinline__ bf16x8 cvt8(float4 a, float4 b) {
    union { bf16x8 v; unsigned int w[4]; } u;
    asm("v_cvt_pk_bf16_f32 %0, %1, %2" : "=v"(u.w[0]) : "v"(a.x), "v"(a.y));
    asm("v_cvt_pk_bf16_f32 %0, %1, %2" : "=v"(u.w[1]) : "v"(a.z), "v"(a.w));
    asm("v_cvt_pk_bf16_f32 %0, %1, %2" : "=v"(u.w[2]) : "v"(b.x), "v"(b.y));
    asm("v_cvt_pk_bf16_f32 %0, %1, %2" : "=v"(u.w[3]) : "v"(b.z), "v"(b.w));
    return u.v;
}

// ---------------- fused preprocessing: weight fusion (blocks < FUSE_BLOCKS) + degree count ----
__global__ void prep_k(const float* __restrict__ wf, const float* __restrict__ bf,
                       const float* __restrict__ wt, const float* __restrict__ bt,
                       const float* __restrict__ w1,
                       ushort_t* __restrict__ WfxT, ushort_t* __restrict__ WtxT,
                       float* __restrict__ bpre,
                       const int* __restrict__ ei, int* __restrict__ deg) {
    if (blockIdx.x >= FUSE_BLOCKS) {
        const int e = (blockIdx.x - FUSE_BLOCKS) * 256 + threadIdx.x;
        if (e < NE) atomicAdd(&deg[ei[NE + e]], 1);
        return;
    }
    const int idx = blockIdx.x * 256 + threadIdx.x;
    const int T1 = H * KP;
    const int T2 = 2 * T1;
    if (idx < T1) {
        const int c = idx >> 9, k = idx & 511;
        float s = 0.f;
        if (k < K_FEAT) {
            #pragma unroll 8
            for (int u = 0; u < 64; ++u) s = fmaf(wf[k * 64 + u], w1[u * 64 + c], s);
        }
        WfxT[idx] = f2bf(s);
    } else if (idx < T2) {
        const int r = idx - T1;
        const int c = r >> 9, k = r & 511;
        float s = 0.f;
        if (k < K_TEXT) {
            #pragma unroll 8
            for (int u = 0; u < 64; ++u) s = fmaf(wt[k * 64 + u], w1[(64 + u) * 64 + c], s);
        }
        WtxT[r] = f2bf(s);
    } else if (idx < T2 + H) {
        const int j = idx - T2;
        float s = 0.f;
        for (int u = 0; u < 64; ++u) s = fmaf(bf[u], w1[u * 64 + j], s);
        for (int u = 0; u < 64; ++u) s = fmaf(bt[u], w1[(64 + u) * 64 + j], s);
        bpre[j] = s;
    }
}

// ---------------- CSR build ----------------
__global__ __launch_bounds__(256)
void partial_k(const int* __restrict__ deg, int* __restrict__ partial) {
    const int b = blockIdx.x;
    const int base = b * NODES_PER_SCAN;
    const int t = threadIdx.x;
    int s = 0;
    for (int i = t; i < NODES_PER_SCAN; i += 256) s += deg[base + i];
    #pragma unroll
    for (int m = 1; m < 64; m <<= 1) s += __shfl_xor(s, m, 64);
    __shared__ int ws[4];
    if ((t & 63) == 0) ws[t >> 6] = s;
    __syncthreads();
    if (t == 0) partial[b] = ws[0] + ws[1] + ws[2] + ws[3];
}

__global__ void scanp_k(const int* __restrict__ partial, int* __restrict__ psum) {
    __shared__ int buf[SCAN_BLOCKS];
    const int t = threadIdx.x;
    if (t < SCAN_BLOCKS) buf[t] = partial[t];
    __syncthreads();
    if (t == 0) {
        int run = 0;
        for (int i = 0; i < SCAN_BLOCKS; ++i) { int v = buf[i]; buf[i] = run; run += v; }
    }
    __syncthreads();
    if (t < SCAN_BLOCKS) psum[t] = buf[t];
}

// offsets + cursor + dinv
__global__ __launch_bounds__(256)
void offsets_k(const int* __restrict__ deg, const int* __restrict__ psum,
               int* __restrict__ row_start, int* __restrict__ cursor,
               float* __restrict__ dinv) {
    const int b = blockIdx.x;
    const int base = b * NODES_PER_SCAN;
    const int t = threadIdx.x;
    __shared__ int tsum[256];
    int loc[4];
    int dg[4];
    int s = 0;
    #pragma unroll
    for (int i = 0; i < 4; ++i) {
        loc[i] = s;
        const int n = t * 4 + i;
        dg[i] = (n < NODES_PER_SCAN) ? deg[base + n] : 0;
        s += dg[i];
    }
    tsum[t] = s;
    __syncthreads();
    #pragma unroll
    for (int off = 1; off < 256; off <<= 1) {
        int v = (t >= off) ? tsum[t - off] : 0;
        __syncthreads();
        tsum[t] += v;
        __syncthreads();
    }
    const int texcl = (t == 0) ? 0 : tsum[t - 1];
    const int bp = psum[b];
    #pragma unroll
    for (int i = 0; i < 4; ++i) {
        const int n = t * 4 + i;
        if (n < NODES_PER_SCAN) {
            const int rs = bp + texcl + loc[i];
            row_start[base + n] = rs;
            cursor[base + n] = rs;
            dinv[base + n] = rsqrtf((float)dg[i] + 1.0f);
        }
    }
}

__global__ void sort_k(const int* __restrict__ ei, int* __restrict__ cursor,
                       int* __restrict__ src_sorted) {
    const int e = blockIdx.x * 256 + threadIdx.x;
    if (e < NE) {
        const int s = ei[e];
        const int d = ei[NE + e];
        const int pos = atomicAdd(&cursor[d], 1);
        src_sorted[pos] = s;
    }
}

// ---------------- GEMM1 (MFMA bf16, dbuf global_load_lds + counted vmcnt, T3/T4) -----------
// u1b[N,64] = bf16((x@Wfx + txt@Wtx + bpre) * dinv)
// Two buffer sets (48KB). Per iter: s_waitcnt vmcnt(6) keeps the NEXT chunk's 6
// DMA ops in flight across the barrier (never drain to 0 in-loop -> the m218
// counted-vmcnt lever), raw s_barrier (no compiler-forced vmcnt(0) drain),
// compute, barrier, re-stage freed buffer with chunk kt+2 (2-iter DMA lead time
// >= HBM latency). Swizzle: pre-swizzled DMA source + XOR read (rule #21).
__global__ __launch_bounds__(256)
void gemm1_mfma(const float* __restrict__ x, const float* __restrict__ txt,
                const ushort_t* __restrict__ WfxT, const ushort_t* __restrict__ WtxT,
                const float* __restrict__ bpre, const float* __restrict__ dinv,
                ushort_t* __restrict__ u1b) {
    __shared__ float As0[BM * 64], As1[BM * 64];      // 16 KB each, 256B rows, swizzled
    __shared__ ushort_t Bs0[H * 64], Bs1[H * 64];     // 8 KB each, 128B rows, swizzled
    const int t = threadIdx.x;
    const int wave = t >> 6, lane = t & 63;
    const int row0 = blockIdx.x * BM;
    const int lr = lane & 15, lq = lane >> 4;

    f32x4 acc[4];
    #pragma unroll
    for (int j = 0; j < 4; ++j) acc[j] = (f32x4){0.f, 0.f, 0.f, 0.f};

    auto stageA = [&](char* ldsa, const float* __restrict__ A, const int KD, const int k0) {
        #pragma unroll
        for (int p = 0; p < 4; ++p) {
            const int P = p * 4096 + t * 16;
            const int row = P >> 8;
            const int kk = ((P & 255) ^ ((row & 7) << 4)) >> 2;
            const int gk = min(k0 + kk, KD - 4);
            const int gr = min(row0 + row, NN - 1);
            __builtin_amdgcn_global_load_lds(
                (const __attribute__((address_space(1))) void*)(A + (long)gr * KD + gk),
                (__attribute__((address_space(3))) void*)(ldsa + P), 16, 0, 0);
        }
    };
    auto stageB = [&](char* ldsb, const ushort_t* __restrict__ WT, const int k0) {
        #pragma unroll
        for (int p = 0; p < 2; ++p) {
            const int P = p * 4096 + t * 16;
            const int row = P >> 7;
            const int kkb = (P & 127) ^ ((row & 7) << 4);
            __builtin_amdgcn_global_load_lds(
                (const __attribute__((address_space(1))) void*)(WT + (long)row * KP + k0 + (kkb >> 1)),
                (__attribute__((address_space(3))) void*)(ldsb + P), 16, 0, 0);
        }
    };
    auto compute = [&](const char* ldsa, const char* ldsb) {
        #pragma unroll
        for (int ks = 0; ks < 2; ++ks) {
            const int ra = wave * 16 + lr;
            const int ka = ks * 128 + lq * 32;
            const int xa = (ra & 7) << 4;
            const float4 c0 = *(const float4*)(ldsa + ra * 256 + (ka ^ xa));
            const float4 c1 = *(const float4*)(ldsa + ra * 256 + ((ka + 16) ^ xa));
            const bf16x8 af = cvt8(c0, c1);
            bf16x8 bfr[4];
            #pragma unroll
            for (int cf = 0; cf < 4; ++cf) {
                const int col = cf * 16 + lr;
                const int kb = ks * 64 + lq * 16;
                bfr[cf] = *(const bf16x8*)(ldsb + col * 128 + (kb ^ ((col & 7) << 4)));
            }
            #pragma unroll
            for (int cf = 0; cf < 4; ++cf)
                acc[cf] = __builtin_amdgcn_mfma_f32_16x16x32_bf16(
                    af, bfr[cf], acc[cf], 0, 0, 0);
        }
    };

    auto phase = [&](const float* __restrict__ A, const ushort_t* __restrict__ WT,
                     auto KD_, auto NT_) {
        constexpr int KD = decltype(KD_)::value;
        constexpr int NT = decltype(NT_)::value;
        stageA((char*)As0, A, KD, 0);  stageB((char*)Bs0, WT, 0);
        stageA((char*)As1, A, KD, 64); stageB((char*)Bs1, WT, 64);
        #pragma unroll
        for (int kt = 0; kt < NT; ++kt) {
            if (kt == NT - 1) asm volatile("s_waitcnt vmcnt(0)" ::: "memory");
            else              asm volatile("s_waitcnt vmcnt(6)" ::: "memory");
            __builtin_amdgcn_s_barrier();        // chunk kt fully landed for all waves
            __builtin_amdgcn_sched_barrier(0);
            if (kt & 1) compute((const char*)As1, (const char*)Bs1);
            else        compute((const char*)As0, (const char*)Bs0);
            __builtin_amdgcn_sched_barrier(0);
            __builtin_amdgcn_s_barrier();        // all waves done reading buf[kt&1]
            if (kt + 2 < NT) {
                if (kt & 1) { stageA((char*)As1, A, KD, (kt + 2) * 64); stageB((char*)Bs1, WT, (kt + 2) * 64); }
                else        { stageA((char*)As0, A, KD, (kt + 2) * 64); stageB((char*)Bs0, WT, (kt + 2) * 64); }
            }
        }
    };

    phase(x, WfxT, IC<K_FEAT>{}, IC<8>{});
    phase(txt, WtxT, IC<K_TEXT>{}, IC<6>{});

    // epilogue: D frag layout col=lane&15, row=(lane>>4)*4+reg; store bf16
    #pragma unroll
    for (int reg = 0; reg < 4; ++reg) {
        const int r = row0 + wave * 16 + lq * 4 + reg;
        if (r < NN) {
            const float di = dinv[r];
            #pragma unroll
            for (int cf = 0; cf < 4; ++cf) {
                const int c = cf * 16 + lr;
                u1b[(long)r * H + c] = f2bf((acc[cf][reg] + bpre[c]) * di);
            }
        }
    }
}

// ---------------- layer1: CSR gather (8 lanes/node, bf16x8 vectorized) + relu + 64->7 ------
__global__ __launch_bounds__(256)
void layer1_csr_k(const int* __restrict__ row_start, const int* __restrict__ deg,
                  const int* __restrict__ src_sorted, const ushort_t* __restrict__ u1b,
                  const float* __restrict__ dinv, const float* __restrict__ b1,
                  const float* __restrict__ w2, float* __restrict__ u2) {
    const int t = threadIdx.x;
    const int lane = t & 63;
    const int g = lane >> 3;
    const int c8 = lane & 7;
    const int node = blockIdx.x * 32 + (t >> 6) * 8 + g;
    if (node >= NN) return;
    const int rs = row_start[node];
    const int dg = deg[node];

    float acc8[8];
    {
        const bf16x8 v = *(const bf16x8*)(u1b + (long)node * H + c8 * 8);
        #pragma unroll
        for (int c = 0; c < 8; ++c) acc8[c] = bf2f((ushort_t)v[c]);
    }
    int j = 0;
    for (; j + 2 <= dg; j += 2) {
        const int s0 = src_sorted[rs + j];
        const int s1 = src_sorted[rs + j + 1];
        const bf16x8 v0 = *(const bf16x8*)(u1b + (long)s0 * H + c8 * 8);
        const bf16x8 v1 = *(const bf16x8*)(u1b + (long)s1 * H + c8 * 8);
        #pragma unroll
        for (int c = 0; c < 8; ++c)
            acc8[c] += bf2f((ushort_t)v0[c]) + bf2f((ushort_t)v1[c]);
    }
    if (j < dg) {
        const int s0 = src_sorted[rs + j];
        const bf16x8 v0 = *(const bf16x8*)(u1b + (long)s0 * H + c8 * 8);
        #pragma unroll
        for (int c = 0; c < 8; ++c) acc8[c] += bf2f((ushort_t)v0[c]);
    }
    const float di = dinv[node];
    float h[8];
    #pragma unroll
    for (int c = 0; c < 8; ++c)
        h[c] = fmaxf(fmaf(di, acc8[c], b1[c8 * 8 + c]), 0.f);
    #pragma unroll
    for (int jj = 0; jj < 7; ++jj) {
        float s = 0.f;
        #pragma unroll
        for (int c = 0; c < 8; ++c)
            s = fmaf(h[c], w2[(c8 * 8 + c) * 7 + jj], s);
        s += __shfl_xor(s, 1, 64);
        s += __shfl_xor(s, 2, 64);
        s += __shfl_xor(s, 4, 64);
        if (c8 == jj) u2[node * 8 + jj] = di * s;
    }
}

// ---------------- layer2: CSR gather-aggregate + final transform ----------------
__global__ __launch_bounds__(256)
void layer2_csr_k(const int* __restrict__ row_start, const int* __restrict__ deg,
                  const int* __restrict__ src_sorted, const float* __restrict__ u2,
                  const float* __restrict__ dinv, const float* __restrict__ b2,
                  float* __restrict__ out) {
    const int t = threadIdx.x;
    const int c = t & 7;
    const int node = blockIdx.x * 32 + (t >> 3);
    if (node >= NN) return;
    const int rs = row_start[node];
    const int dg = deg[node];
    float acc = (c < 7) ? u2[node * 8 + c] : 0.f;   // self
    int j = 0;
    for (; j + 4 <= dg; j += 4) {
        const int s0 = src_sorted[rs + j];
        const int s1 = src_sorted[rs + j + 1];
        const int s2 = src_sorted[rs + j + 2];
        const int s3 = src_sorted[rs + j + 3];
        if (c < 7) {
            acc += u2[s0 * 8 + c];
            acc += u2[s1 * 8 + c];
            acc += u2[s2 * 8 + c];
            acc += u2[s3 * 8 + c];
        }
    }
    for (; j < dg; ++j) {
        const int s = src_sorted[rs + j];
        if (c < 7) acc += u2[s * 8 + c];
    }
    if (c < 7) out[node * 7 + c] = dinv[node] * acc + b2[c];
}

extern "C" void kernel_launch(void* const* d_in, const int* in_sizes, int n_in,
                              void* d_out, int out_size, void* d_ws, size_t ws_size,
                              hipStream_t stream) {
    const float* x      = (const float*)d_in[0];
    const float* txt    = (const float*)d_in[1];
    const int*   ei     = (const int*)d_in[2];
    const float* w_feat = (const float*)d_in[3];
    const float* b_feat = (const float*)d_in[4];
    const float* w_text = (const float*)d_in[5];
    const float* b_text = (const float*)d_in[6];
    const float* w1     = (const float*)d_in[7];
    const float* b1     = (const float*)d_in[8];
    const float* w2     = (const float*)d_in[9];
    const float* b2     = (const float*)d_in[10];
    float* out = (float*)d_out;

    char* p = (char*)d_ws;
    auto alloc = [&](size_t bytes) {
        char* r = p;
        p += (bytes + 255) & ~(size_t)255;
        return r;
    };
    ushort_t* WfxT = (ushort_t*)alloc((size_t)H * KP * 2);
    ushort_t* WtxT = (ushort_t*)alloc((size_t)H * KP * 2);
    float* bpre = (float*)alloc(H * 4);
    int*   deg  = (int*)alloc((size_t)NN * 4);
    float* dinv = (float*)alloc((size_t)NN * 4);
    int*   row_start = (int*)alloc((size_t)NN * 4);
    int*   cursor    = (int*)alloc((size_t)NN * 4);
    int*   partial   = (int*)alloc((size_t)SCAN_BLOCKS * 4);
    int*   psum      = (int*)alloc((size_t)SCAN_BLOCKS * 4);
    int*   src_sorted = (int*)alloc((size_t)NE * 4);
    ushort_t* u1b = (ushort_t*)alloc((size_t)NN * H * 2);
    float* u2   = (float*)alloc((size_t)NN * 8 * 4);

    hipMemsetAsync(deg, 0, (size_t)NN * 4, stream);

    const int deg_blocks = (NE + 255) / 256;
    prep_k<<<FUSE_BLOCKS + deg_blocks, 256, 0, stream>>>(w_feat, b_feat, w_text, b_text, w1,
                                                         WfxT, WtxT, bpre, ei, deg);
    partial_k<<<SCAN_BLOCKS, 256, 0, stream>>>(deg, partial);
    scanp_k<<<1, 128, 0, stream>>>(partial, psum);
    offsets_k<<<SCAN_BLOCKS, 256, 0, stream>>>(deg, psum, row_start, cursor, dinv);
    sort_k<<<(NE + 255) / 256, 256, 0, stream>>>(ei, cursor, src_sorted);
    gemm1_mfma<<<(NN + BM - 1) / BM, 256, 0, stream>>>(x, txt, WfxT, WtxT, bpre, dinv, u1b);
    layer1_csr_k<<<(NN + 31) / 32, 256, 0, stream>>>(row_start, deg, src_sorted, u1b,
                                                     dinv, b1, w2, u2);
    layer2_csr_k<<<(NN + 31) / 32, 256, 0, stream>>>(row_start, deg, src_sorted, u2,
                                                     dinv, b2, out);
}